// Round 1
// baseline (1881.713 us; speedup 1.0000x reference)
//
#include <hip/hip_runtime.h>
#include <math.h>

// ---------------- init / histogram / norm ----------------

__global__ void zero_i32(int* __restrict__ p, int n) {
    int i = blockIdx.x * blockDim.x + threadIdx.x;
    if (i < n) p[i] = 0;
}

__global__ void hist_k(const int* __restrict__ dst, int E, int* __restrict__ counts) {
    int e = blockIdx.x * blockDim.x + threadIdx.x;
    if (e < E) atomicAdd(&counts[dst[e]], 1);
}

__global__ void dinv_k(const int* __restrict__ counts, float* __restrict__ dinv, int N) {
    int i = blockIdx.x * blockDim.x + threadIdx.x;
    if (i < N) dinv[i] = rsqrtf((float)(counts[i] + 1));  // +1 self-loop
}

// ---------------- 3-pass exclusive scan (1024 elems / block) ----------------

__global__ void scan_pass1(const int* __restrict__ counts, int N, int* __restrict__ bsum) {
    __shared__ int s[256];
    int t = threadIdx.x;
    int base = blockIdx.x * 1024 + t * 4;
    int sum = 0;
    for (int j = 0; j < 4; ++j) { int i = base + j; if (i < N) sum += counts[i]; }
    s[t] = sum; __syncthreads();
    for (int off = 128; off > 0; off >>= 1) {
        if (t < off) s[t] += s[t + off];
        __syncthreads();
    }
    if (t == 0) bsum[blockIdx.x] = s[0];
}

__global__ void scan_pass2(const int* __restrict__ bsum, int nb, int* __restrict__ boff) {
    if (blockIdx.x == 0 && threadIdx.x == 0) {
        int r = 0;
        for (int b = 0; b < nb; ++b) { boff[b] = r; r += bsum[b]; }
    }
}

__global__ void scan_pass3(const int* __restrict__ counts, int N,
                           const int* __restrict__ boff, int* __restrict__ rowptr, int E) {
    __shared__ int s[256];
    int t = threadIdx.x;
    int base = blockIdx.x * 1024 + t * 4;
    int c[4]; int sum = 0;
    for (int j = 0; j < 4; ++j) { int i = base + j; c[j] = (i < N) ? counts[i] : 0; sum += c[j]; }
    s[t] = sum; __syncthreads();
    for (int off = 1; off < 256; off <<= 1) {
        int v = (t >= off) ? s[t - off] : 0;
        __syncthreads();
        s[t] += v;
        __syncthreads();
    }
    int excl = s[t] - sum + boff[blockIdx.x];
    for (int j = 0; j < 4; ++j) {
        int i = base + j;
        if (i < N) { rowptr[i] = excl; excl += c[j]; }
    }
    if (blockIdx.x == 0 && t == 0) rowptr[N] = E;
}

// ---------------- CSR fill ----------------

__global__ void fill_k(const int* __restrict__ src, const int* __restrict__ dst, int E,
                       const float* __restrict__ dinv, const int* __restrict__ rowptr,
                       int* __restrict__ cursor, int* __restrict__ col, float* __restrict__ valv) {
    int e = blockIdx.x * blockDim.x + threadIdx.x;
    if (e >= E) return;
    int s = src[e], d = dst[e];
    int pos = rowptr[d] + atomicAdd(&cursor[d], 1);
    col[pos]  = s;
    valv[pos] = dinv[s] * dinv[d];
}

// ---------------- g0 = x @ W  (N x 128) * (128 x 64) ----------------

__global__ void __launch_bounds__(256) gemm_k(const float* __restrict__ x,
                                              const float* __restrict__ W,
                                              float* __restrict__ g0, int N) {
    __shared__ float Ws[128 * 64];
    for (int i = threadIdx.x; i < 128 * 64; i += blockDim.x) Ws[i] = W[i];
    __syncthreads();
    int lane = threadIdx.x & 63;
    int wib  = threadIdx.x >> 6;
    int gw = blockIdx.x * (blockDim.x >> 6) + wib;
    int stride = gridDim.x * (blockDim.x >> 6);
    for (int n = gw; n < N; n += stride) {
        float xa = x[(size_t)n * 128 + lane];
        float xb = x[(size_t)n * 128 + 64 + lane];
        float acc = 0.f;
#pragma unroll
        for (int k = 0; k < 64; ++k) acc += __shfl(xa, k, 64) * Ws[k * 64 + lane];
#pragma unroll
        for (int k = 0; k < 64; ++k) acc += __shfl(xb, k, 64) * Ws[(64 + k) * 64 + lane];
        g0[(size_t)n * 64 + lane] = acc;
    }
}

// ---------------- propagation: g_out = 0.9 * A_hat g_in + 0.1 * g0 ----------------
// one wave per destination node; lane = feature column (D_OUT = 64 = wave size)

__global__ void __launch_bounds__(256) prop_k(const float* __restrict__ gin,
                                              const float* __restrict__ g0,
                                              float* __restrict__ gout,
                                              const int* __restrict__ rowptr,
                                              const int* __restrict__ col,
                                              const float* __restrict__ valv,
                                              const float* __restrict__ dinv,
                                              const float* __restrict__ bias,
                                              int N, int final_step) {
    int gw = (blockIdx.x * blockDim.x + threadIdx.x) >> 6;
    int lane = threadIdx.x & 63;
    if (gw >= N) return;
    int beg = rowptr[gw], end = rowptr[gw + 1];
    float di = dinv[gw];
    size_t ro = (size_t)gw * 64 + lane;
    float acc = di * di * gin[ro];  // self-loop: norm = dinv[n]^2
    int p = beg;
    for (; p + 3 < end; p += 4) {
        int   c0 = col[p],     c1 = col[p + 1], c2 = col[p + 2], c3 = col[p + 3];
        float w0 = valv[p],    w1 = valv[p + 1], w2 = valv[p + 2], w3 = valv[p + 3];
        float a0 = gin[(size_t)c0 * 64 + lane];
        float a1 = gin[(size_t)c1 * 64 + lane];
        float a2 = gin[(size_t)c2 * 64 + lane];
        float a3 = gin[(size_t)c3 * 64 + lane];
        acc += w0 * a0; acc += w1 * a1; acc += w2 * a2; acc += w3 * a3;
    }
    for (; p < end; ++p) acc += valv[p] * gin[(size_t)col[p] * 64 + lane];
    float r = 0.9f * acc + 0.1f * g0[ro];
    if (final_step) r += bias[lane];
    gout[ro] = r;
}

// ---------------- launch ----------------

extern "C" void kernel_launch(void* const* d_in, const int* in_sizes, int n_in,
                              void* d_out, int out_size, void* d_ws, size_t ws_size,
                              hipStream_t stream) {
    const float* x  = (const float*)d_in[0];
    const int*   ei = (const int*)d_in[1];
    const float* W  = (const float*)d_in[2];
    const float* b  = (const float*)d_in[3];
    float* out = (float*)d_out;

    const int N = in_sizes[0] / 128;
    const int E = in_sizes[1] / 2;
    const int* src = ei;
    const int* dst = ei + E;

    // workspace carve-up (256 B aligned)
    char* w = (char*)d_ws;
    size_t off = 0;
    auto alloc = [&](size_t bytes) -> void* {
        void* p = w + off;
        off += (bytes + 255) & ~(size_t)255;
        return p;
    };
    float* g0     = (float*)alloc((size_t)N * 64 * 4);
    float* bufA   = (float*)alloc((size_t)N * 64 * 4);
    float* bufB   = (float*)alloc((size_t)N * 64 * 4);
    int*   col    = (int*)  alloc((size_t)E * 4);
    float* valv   = (float*)alloc((size_t)E * 4);
    int*   rowptr = (int*)  alloc((size_t)(N + 1) * 4);
    int*   counts = (int*)  alloc((size_t)N * 4);
    float* dinvv  = (float*)alloc((size_t)N * 4);
    const int nb = (N + 1023) / 1024;
    int*   bsum   = (int*)  alloc((size_t)nb * 4);
    int*   boff   = (int*)  alloc((size_t)nb * 4);

    const int nblkN = (N + 255) / 256;
    const int nblkE = (E + 255) / 256;

    // build normalized adjacency (CSR by dst)
    zero_i32<<<nblkN, 256, 0, stream>>>(counts, N);
    hist_k<<<nblkE, 256, 0, stream>>>(dst, E, counts);
    dinv_k<<<nblkN, 256, 0, stream>>>(counts, dinvv, N);
    scan_pass1<<<nb, 256, 0, stream>>>(counts, N, bsum);
    scan_pass2<<<1, 64, 0, stream>>>(bsum, nb, boff);
    scan_pass3<<<nb, 256, 0, stream>>>(counts, N, boff, rowptr, E);
    zero_i32<<<nblkN, 256, 0, stream>>>(counts, N);  // reuse as fill cursor
    fill_k<<<nblkE, 256, 0, stream>>>(src, dst, E, dinvv, rowptr, counts, col, valv);

    // g0 = x @ W (propagation commutes with the linear head: (A h) W = A (h W))
    gemm_k<<<2048, 256, 0, stream>>>(x, W, g0, N);

    // K = 10 APPNP steps, ping-pong; last step writes d_out and adds bias
    const int nblkP = (N * 64 + 255) / 256;
    const float* gin = g0;
    float* pp[2] = {bufA, bufB};
    for (int k = 0; k < 10; ++k) {
        const bool fin = (k == 9);
        float* gout = fin ? out : pp[k & 1];
        prop_k<<<nblkP, 256, 0, stream>>>(gin, g0, gout, rowptr, col, valv, dinvv, b, N, fin ? 1 : 0);
        gin = gout;
    }
}

// Round 2
// 1646.571 us; speedup vs baseline: 1.1428x; 1.1428x over previous
//
#include <hip/hip_runtime.h>
#include <hip/hip_fp16.h>
#include <math.h>

// ---------------- init / histogram / norm ----------------

__global__ void zero_i32(int* __restrict__ p, int n) {
    int i = blockIdx.x * blockDim.x + threadIdx.x;
    if (i < n) p[i] = 0;
}

__global__ void hist_k(const int* __restrict__ dst, int E, int* __restrict__ counts) {
    int e = blockIdx.x * blockDim.x + threadIdx.x;
    if (e < E) atomicAdd(&counts[dst[e]], 1);
}

__global__ void dinv_k(const int* __restrict__ counts, float* __restrict__ dinv, int N) {
    int i = blockIdx.x * blockDim.x + threadIdx.x;
    if (i < N) dinv[i] = rsqrtf((float)(counts[i] + 1));  // +1 self-loop
}

// ---------------- 3-pass exclusive scan (1024 elems / block) ----------------

__global__ void scan_pass1(const int* __restrict__ counts, int N, int* __restrict__ bsum) {
    __shared__ int s[256];
    int t = threadIdx.x;
    int base = blockIdx.x * 1024 + t * 4;
    int sum = 0;
    for (int j = 0; j < 4; ++j) { int i = base + j; if (i < N) sum += counts[i]; }
    s[t] = sum; __syncthreads();
    for (int off = 128; off > 0; off >>= 1) {
        if (t < off) s[t] += s[t + off];
        __syncthreads();
    }
    if (t == 0) bsum[blockIdx.x] = s[0];
}

__global__ void scan_pass2(const int* __restrict__ bsum, int nb, int* __restrict__ boff) {
    if (blockIdx.x == 0 && threadIdx.x == 0) {
        int r = 0;
        for (int b = 0; b < nb; ++b) { boff[b] = r; r += bsum[b]; }
    }
}

__global__ void scan_pass3(const int* __restrict__ counts, int N,
                           const int* __restrict__ boff, int* __restrict__ rowptr, int E) {
    __shared__ int s[256];
    int t = threadIdx.x;
    int base = blockIdx.x * 1024 + t * 4;
    int c[4]; int sum = 0;
    for (int j = 0; j < 4; ++j) { int i = base + j; c[j] = (i < N) ? counts[i] : 0; sum += c[j]; }
    s[t] = sum; __syncthreads();
    for (int off = 1; off < 256; off <<= 1) {
        int v = (t >= off) ? s[t - off] : 0;
        __syncthreads();
        s[t] += v;
        __syncthreads();
    }
    int excl = s[t] - sum + boff[blockIdx.x];
    for (int j = 0; j < 4; ++j) {
        int i = base + j;
        if (i < N) { rowptr[i] = excl; excl += c[j]; }
    }
    if (blockIdx.x == 0 && t == 0) rowptr[N] = E;
}

// ---------------- CSR fill: packed (col, val) as 8B uint2 ----------------

__global__ void fill_k(const int* __restrict__ src, const int* __restrict__ dst, int E,
                       const float* __restrict__ dinv, const int* __restrict__ rowptr,
                       int* __restrict__ cursor, uint2* __restrict__ edges) {
    int e = blockIdx.x * blockDim.x + threadIdx.x;
    if (e >= E) return;
    int s = src[e], d = dst[e];
    int pos = rowptr[d] + atomicAdd(&cursor[d], 1);
    float v = dinv[s] * dinv[d];
    edges[pos] = make_uint2((unsigned)s, __float_as_uint(v));
}

// ---------------- g0 = x @ W : LDS-tiled, 128 rows x 64 cols per block ----------------
// Also emits the fp16 copy used as the gather buffer for prop step 0.

__global__ void __launch_bounds__(256) gemm_k(const float* __restrict__ x,
                                              const float* __restrict__ W,
                                              float* __restrict__ g0,
                                              __half* __restrict__ g0h, int N) {
    __shared__ float Ws[128 * 64];    // 32 KB, row-major [k][j]
    __shared__ float xs[128 * 133];   // 68 KB, stride 133 -> conflict-free compute reads
    int t = threadIdx.x;
    for (int i = t; i < 128 * 64; i += 256) Ws[i] = W[i];
    int n0 = blockIdx.x * 128;
    for (int f = t; f < 128 * 32; f += 256) {  // f indexes a float4: r = f>>5, c4 = f&31
        int r = f >> 5, c4 = f & 31;
        int n = n0 + r;
        float4 v = (n < N) ? ((const float4*)x)[(size_t)n * 32 + c4]
                           : make_float4(0.f, 0.f, 0.f, 0.f);
        float* dp = &xs[r * 133 + c4 * 4];
        dp[0] = v.x; dp[1] = v.y; dp[2] = v.z; dp[3] = v.w;
    }
    __syncthreads();
    int tr = t & 15, tc = t >> 4;      // j0 = 4*tr (cols), r0 = 8*tc (rows)
    int j0 = tr * 4, r0 = tc * 8;
    float acc[8][4] = {};
#pragma unroll 4
    for (int k = 0; k < 128; ++k) {
        float4 wv = *(const float4*)&Ws[k * 64 + j0];
#pragma unroll
        for (int i = 0; i < 8; ++i) {
            float xv = xs[(r0 + i) * 133 + k];
            acc[i][0] += xv * wv.x; acc[i][1] += xv * wv.y;
            acc[i][2] += xv * wv.z; acc[i][3] += xv * wv.w;
        }
    }
#pragma unroll
    for (int i = 0; i < 8; ++i) {
        int n = n0 + r0 + i;
        if (n < N) {
            float4 v = make_float4(acc[i][0], acc[i][1], acc[i][2], acc[i][3]);
            *(float4*)&g0[(size_t)n * 64 + j0] = v;
            __half2 h01 = __floats2half2_rn(v.x, v.y);
            __half2 h23 = __floats2half2_rn(v.z, v.w);
            *(__half2*)&g0h[(size_t)n * 64 + j0]     = h01;
            *(__half2*)&g0h[(size_t)n * 64 + j0 + 2] = h23;
        }
    }
}

// ---------------- propagation: g_out = 0.9 * A_hat g_in + 0.1 * g0 ----------------
// one wave per destination node; lane = feature (D=64). Gather buffer is fp16
// (halves cache-line traffic); accumulation stays fp32; g0 term stays fp32.

__global__ void __launch_bounds__(256) prop_k(const __half* __restrict__ gin,
                                              const float* __restrict__ g0,
                                              __half* __restrict__ gout,
                                              float* __restrict__ outf,
                                              const int* __restrict__ rowptr,
                                              const uint2* __restrict__ edges,
                                              const float* __restrict__ dinv,
                                              const float* __restrict__ bias,
                                              int N, int final_step) {
    int gw = (blockIdx.x * blockDim.x + threadIdx.x) >> 6;
    int lane = threadIdx.x & 63;
    if (gw >= N) return;
    int beg = rowptr[gw], end = rowptr[gw + 1];
    float di = dinv[gw];
    size_t ro = (size_t)gw * 64 + lane;
    float acc = di * di * __half2float(gin[ro]);  // self-loop: norm = dinv[n]^2
    int p = beg;
    for (; p + 3 < end; p += 4) {
        uint2 e0 = edges[p], e1 = edges[p + 1], e2 = edges[p + 2], e3 = edges[p + 3];
        float a0 = __half2float(gin[(size_t)e0.x * 64 + lane]);
        float a1 = __half2float(gin[(size_t)e1.x * 64 + lane]);
        float a2 = __half2float(gin[(size_t)e2.x * 64 + lane]);
        float a3 = __half2float(gin[(size_t)e3.x * 64 + lane]);
        acc += __uint_as_float(e0.y) * a0;
        acc += __uint_as_float(e1.y) * a1;
        acc += __uint_as_float(e2.y) * a2;
        acc += __uint_as_float(e3.y) * a3;
    }
    for (; p < end; ++p) {
        uint2 e = edges[p];
        acc += __uint_as_float(e.y) * __half2float(gin[(size_t)e.x * 64 + lane]);
    }
    float r = 0.9f * acc + 0.1f * g0[ro];
    if (final_step) outf[ro] = r + bias[lane];
    else            gout[ro] = __float2half(r);
}

// ---------------- launch ----------------

extern "C" void kernel_launch(void* const* d_in, const int* in_sizes, int n_in,
                              void* d_out, int out_size, void* d_ws, size_t ws_size,
                              hipStream_t stream) {
    const float* x  = (const float*)d_in[0];
    const int*   ei = (const int*)d_in[1];
    const float* W  = (const float*)d_in[2];
    const float* b  = (const float*)d_in[3];
    float* out = (float*)d_out;

    const int N = in_sizes[0] / 128;
    const int E = in_sizes[1] / 2;
    const int* src = ei;
    const int* dst = ei + E;

    // workspace carve-up (256 B aligned)
    char* w = (char*)d_ws;
    size_t off = 0;
    auto alloc = [&](size_t bytes) -> void* {
        void* p = w + off;
        off += (bytes + 255) & ~(size_t)255;
        return p;
    };
    float*  g0     = (float*) alloc((size_t)N * 64 * 4);
    __half* g0h    = (__half*)alloc((size_t)N * 64 * 2);
    __half* bufA   = (__half*)alloc((size_t)N * 64 * 2);
    __half* bufB   = (__half*)alloc((size_t)N * 64 * 2);
    uint2*  edges  = (uint2*) alloc((size_t)E * 8);
    int*    rowptr = (int*)   alloc((size_t)(N + 1) * 4);
    int*    counts = (int*)   alloc((size_t)N * 4);
    float*  dinvv  = (float*) alloc((size_t)N * 4);
    const int nb = (N + 1023) / 1024;
    int*    bsum   = (int*)   alloc((size_t)nb * 4);
    int*    boff   = (int*)   alloc((size_t)nb * 4);

    const int nblkN = (N + 255) / 256;
    const int nblkE = (E + 255) / 256;

    // build normalized adjacency (CSR by dst, packed col+val)
    zero_i32<<<nblkN, 256, 0, stream>>>(counts, N);
    hist_k<<<nblkE, 256, 0, stream>>>(dst, E, counts);
    dinv_k<<<nblkN, 256, 0, stream>>>(counts, dinvv, N);
    scan_pass1<<<nb, 256, 0, stream>>>(counts, N, bsum);
    scan_pass2<<<1, 64, 0, stream>>>(bsum, nb, boff);
    scan_pass3<<<nb, 256, 0, stream>>>(counts, N, boff, rowptr, E);
    zero_i32<<<nblkN, 256, 0, stream>>>(counts, N);  // reuse as fill cursor
    fill_k<<<nblkE, 256, 0, stream>>>(src, dst, E, dinvv, rowptr, counts, edges);

    // g0 = x @ W (propagation commutes with the linear head: (A h) W = A (h W))
    gemm_k<<<(N + 127) / 128, 256, 0, stream>>>(x, W, g0, g0h, N);

    // K = 10 APPNP steps, fp16 ping-pong; last step writes fp32 d_out (+bias)
    const int nblkP = (N * 64 + 255) / 256;
    const __half* gin = g0h;
    __half* pp[2] = {bufA, bufB};
    for (int k = 0; k < 10; ++k) {
        const bool fin = (k == 9);
        __half* gout = pp[k & 1];
        prop_k<<<nblkP, 256, 0, stream>>>(gin, g0, gout, out, rowptr, edges,
                                          dinvv, b, N, fin ? 1 : 0);
        gin = gout;
    }
}

// Round 3
// 1219.950 us; speedup vs baseline: 1.5425x; 1.3497x over previous
//
#include <hip/hip_runtime.h>
#include <hip/hip_fp16.h>
#include <math.h>

// ---------------- init / histogram / norm ----------------

__global__ void zero_i32(int* __restrict__ p, int n) {
    int i = blockIdx.x * blockDim.x + threadIdx.x;
    if (i < n) p[i] = 0;
}

__global__ void hist_k(const int* __restrict__ dst, int E, int* __restrict__ counts) {
    int e = blockIdx.x * blockDim.x + threadIdx.x;
    if (e < E) atomicAdd(&counts[dst[e]], 1);
}

__global__ void dinv_k(const int* __restrict__ counts, float* __restrict__ dinv, int N) {
    int i = blockIdx.x * blockDim.x + threadIdx.x;
    if (i < N) dinv[i] = rsqrtf((float)(counts[i] + 1));  // +1 self-loop
}

// ---------------- 3-pass exclusive scan (1024 elems / block) ----------------

__global__ void scan_pass1(const int* __restrict__ counts, int N, int* __restrict__ bsum) {
    __shared__ int s[256];
    int t = threadIdx.x;
    int base = blockIdx.x * 1024 + t * 4;
    int sum = 0;
    for (int j = 0; j < 4; ++j) { int i = base + j; if (i < N) sum += counts[i]; }
    s[t] = sum; __syncthreads();
    for (int off = 128; off > 0; off >>= 1) {
        if (t < off) s[t] += s[t + off];
        __syncthreads();
    }
    if (t == 0) bsum[blockIdx.x] = s[0];
}

__global__ void scan_pass2(const int* __restrict__ bsum, int nb, int* __restrict__ boff) {
    if (blockIdx.x == 0 && threadIdx.x == 0) {
        int r = 0;
        for (int b = 0; b < nb; ++b) { boff[b] = r; r += bsum[b]; }
    }
}

__global__ void scan_pass3(const int* __restrict__ counts, int N,
                           const int* __restrict__ boff, int* __restrict__ rowptr, int E) {
    __shared__ int s[256];
    int t = threadIdx.x;
    int base = blockIdx.x * 1024 + t * 4;
    int c[4]; int sum = 0;
    for (int j = 0; j < 4; ++j) { int i = base + j; c[j] = (i < N) ? counts[i] : 0; sum += c[j]; }
    s[t] = sum; __syncthreads();
    for (int off = 1; off < 256; off <<= 1) {
        int v = (t >= off) ? s[t - off] : 0;
        __syncthreads();
        s[t] += v;
        __syncthreads();
    }
    int excl = s[t] - sum + boff[blockIdx.x];
    for (int j = 0; j < 4; ++j) {
        int i = base + j;
        if (i < N) { rowptr[i] = excl; excl += c[j]; }
    }
    if (blockIdx.x == 0 && t == 0) rowptr[N] = E;
}

// ---------------- CSR fill: packed (col, val) as 8B uint2 ----------------

__global__ void fill_k(const int* __restrict__ src, const int* __restrict__ dst, int E,
                       const float* __restrict__ dinv, const int* __restrict__ rowptr,
                       int* __restrict__ cursor, uint2* __restrict__ edges) {
    int e = blockIdx.x * blockDim.x + threadIdx.x;
    if (e >= E) return;
    int s = src[e], d = dst[e];
    int pos = rowptr[d] + atomicAdd(&cursor[d], 1);
    float v = dinv[s] * dinv[d];
    edges[pos] = make_uint2((unsigned)s, __float_as_uint(v));
}

// ---------------- g0 = x @ W : LDS-tiled, 128 rows x 64 cols per block ----------------
// Also emits the fp16 copy used as the gather buffer for prop step 0.

__global__ void __launch_bounds__(256) gemm_k(const float* __restrict__ x,
                                              const float* __restrict__ W,
                                              float* __restrict__ g0,
                                              __half* __restrict__ g0h, int N) {
    __shared__ float Ws[128 * 64];    // 32 KB, row-major [k][j]
    __shared__ float xs[128 * 133];   // 68 KB, stride 133 -> conflict-free compute reads
    int t = threadIdx.x;
    for (int i = t; i < 128 * 64; i += 256) Ws[i] = W[i];
    int n0 = blockIdx.x * 128;
    for (int f = t; f < 128 * 32; f += 256) {  // f indexes a float4: r = f>>5, c4 = f&31
        int r = f >> 5, c4 = f & 31;
        int n = n0 + r;
        float4 v = (n < N) ? ((const float4*)x)[(size_t)n * 32 + c4]
                           : make_float4(0.f, 0.f, 0.f, 0.f);
        float* dp = &xs[r * 133 + c4 * 4];
        dp[0] = v.x; dp[1] = v.y; dp[2] = v.z; dp[3] = v.w;
    }
    __syncthreads();
    int tr = t & 15, tc = t >> 4;      // j0 = 4*tr (cols), r0 = 8*tc (rows)
    int j0 = tr * 4, r0 = tc * 8;
    float acc[8][4] = {};
#pragma unroll 4
    for (int k = 0; k < 128; ++k) {
        float4 wv = *(const float4*)&Ws[k * 64 + j0];
#pragma unroll
        for (int i = 0; i < 8; ++i) {
            float xv = xs[(r0 + i) * 133 + k];
            acc[i][0] += xv * wv.x; acc[i][1] += xv * wv.y;
            acc[i][2] += xv * wv.z; acc[i][3] += xv * wv.w;
        }
    }
#pragma unroll
    for (int i = 0; i < 8; ++i) {
        int n = n0 + r0 + i;
        if (n < N) {
            float4 v = make_float4(acc[i][0], acc[i][1], acc[i][2], acc[i][3]);
            *(float4*)&g0[(size_t)n * 64 + j0] = v;
            __half2 h01 = __floats2half2_rn(v.x, v.y);
            __half2 h23 = __floats2half2_rn(v.z, v.w);
            *(__half2*)&g0h[(size_t)n * 64 + j0]     = h01;
            *(__half2*)&g0h[(size_t)n * 64 + j0 + 2] = h23;
        }
    }
}

// ---------------- propagation: g_out = 0.9 * A_hat g_in + 0.1 * g0 ----------------
// One wave per destination row; lane = feature (D=64).
// Edge list for the row is fetched with ONE coalesced lane-parallel load
// (lane j holds edge beg+base+j), then broadcast per-edge via v_readlane —
// removing the serial (edge-load -> gather) latency chain. Inner loop is
// pure independent gathers -> deep memory-level parallelism.

__global__ void __launch_bounds__(256) prop_k(const __half* __restrict__ gin,
                                              const float* __restrict__ g0,
                                              __half* __restrict__ gout,
                                              float* __restrict__ outf,
                                              const int* __restrict__ rowptr,
                                              const uint2* __restrict__ edges,
                                              const float* __restrict__ dinv,
                                              const float* __restrict__ bias,
                                              int N, int final_step) {
    int gw = (blockIdx.x * blockDim.x + threadIdx.x) >> 6;
    int lane = threadIdx.x & 63;
    if (gw >= N) return;
    int beg = rowptr[gw], end = rowptr[gw + 1];
    int deg = end - beg;
    float di = dinv[gw];
    size_t ro = (size_t)gw * 64 + lane;
    float acc = di * di * __half2float(gin[ro]);  // self-loop: norm = dinv[n]^2

    for (int base = 0; base < deg; base += 64) {
        int m = deg - base; if (m > 64) m = 64;
        int idx = beg + base + lane;
        if (lane >= m) idx = beg;                 // keep OOB lanes in-bounds
        uint2 e = edges[idx];                     // one coalesced 8B/lane load
        int      ci = (int)e.x;
        unsigned wu = e.y;

        int j = 0;
        for (; j + 3 < m; j += 4) {
            int c0 = __builtin_amdgcn_readlane(ci, j);
            int c1 = __builtin_amdgcn_readlane(ci, j + 1);
            int c2 = __builtin_amdgcn_readlane(ci, j + 2);
            int c3 = __builtin_amdgcn_readlane(ci, j + 3);
            float w0 = __uint_as_float(__builtin_amdgcn_readlane((int)wu, j));
            float w1 = __uint_as_float(__builtin_amdgcn_readlane((int)wu, j + 1));
            float w2 = __uint_as_float(__builtin_amdgcn_readlane((int)wu, j + 2));
            float w3 = __uint_as_float(__builtin_amdgcn_readlane((int)wu, j + 3));
            float a0 = __half2float(gin[(size_t)c0 * 64 + lane]);
            float a1 = __half2float(gin[(size_t)c1 * 64 + lane]);
            float a2 = __half2float(gin[(size_t)c2 * 64 + lane]);
            float a3 = __half2float(gin[(size_t)c3 * 64 + lane]);
            acc += w0 * a0; acc += w1 * a1; acc += w2 * a2; acc += w3 * a3;
        }
        for (; j < m; ++j) {
            int   c = __builtin_amdgcn_readlane(ci, j);
            float w = __uint_as_float(__builtin_amdgcn_readlane((int)wu, j));
            acc += w * __half2float(gin[(size_t)c * 64 + lane]);
        }
    }

    float r = 0.9f * acc + 0.1f * g0[ro];
    if (final_step) outf[ro] = r + bias[lane];
    else            gout[ro] = __float2half(r);
}

// ---------------- launch ----------------

extern "C" void kernel_launch(void* const* d_in, const int* in_sizes, int n_in,
                              void* d_out, int out_size, void* d_ws, size_t ws_size,
                              hipStream_t stream) {
    const float* x  = (const float*)d_in[0];
    const int*   ei = (const int*)d_in[1];
    const float* W  = (const float*)d_in[2];
    const float* b  = (const float*)d_in[3];
    float* out = (float*)d_out;

    const int N = in_sizes[0] / 128;
    const int E = in_sizes[1] / 2;
    const int* src = ei;
    const int* dst = ei + E;

    // workspace carve-up (256 B aligned)
    char* w = (char*)d_ws;
    size_t off = 0;
    auto alloc = [&](size_t bytes) -> void* {
        void* p = w + off;
        off += (bytes + 255) & ~(size_t)255;
        return p;
    };
    float*  g0     = (float*) alloc((size_t)N * 64 * 4);
    __half* g0h    = (__half*)alloc((size_t)N * 64 * 2);
    __half* bufA   = (__half*)alloc((size_t)N * 64 * 2);
    __half* bufB   = (__half*)alloc((size_t)N * 64 * 2);
    uint2*  edges  = (uint2*) alloc((size_t)E * 8);
    int*    rowptr = (int*)   alloc((size_t)(N + 1) * 4);
    int*    counts = (int*)   alloc((size_t)N * 4);
    float*  dinvv  = (float*) alloc((size_t)N * 4);
    const int nb = (N + 1023) / 1024;
    int*    bsum   = (int*)   alloc((size_t)nb * 4);
    int*    boff   = (int*)   alloc((size_t)nb * 4);

    const int nblkN = (N + 255) / 256;
    const int nblkE = (E + 255) / 256;

    // build normalized adjacency (CSR by dst, packed col+val)
    zero_i32<<<nblkN, 256, 0, stream>>>(counts, N);
    hist_k<<<nblkE, 256, 0, stream>>>(dst, E, counts);
    dinv_k<<<nblkN, 256, 0, stream>>>(counts, dinvv, N);
    scan_pass1<<<nb, 256, 0, stream>>>(counts, N, bsum);
    scan_pass2<<<1, 64, 0, stream>>>(bsum, nb, boff);
    scan_pass3<<<nb, 256, 0, stream>>>(counts, N, boff, rowptr, E);
    zero_i32<<<nblkN, 256, 0, stream>>>(counts, N);  // reuse as fill cursor
    fill_k<<<nblkE, 256, 0, stream>>>(src, dst, E, dinvv, rowptr, counts, edges);

    // g0 = x @ W (propagation commutes with the linear head: (A h) W = A (h W))
    gemm_k<<<(N + 127) / 128, 256, 0, stream>>>(x, W, g0, g0h, N);

    // K = 10 APPNP steps, fp16 ping-pong; last step writes fp32 d_out (+bias)
    const int nblkP = (N * 64 + 255) / 256;
    const __half* gin = g0h;
    __half* pp[2] = {bufA, bufB};
    for (int k = 0; k < 10; ++k) {
        const bool fin = (k == 9);
        __half* gout = pp[k & 1];
        prop_k<<<nblkP, 256, 0, stream>>>(gin, g0, gout, out, rowptr, edges,
                                          dinvv, b, N, fin ? 1 : 0);
        gin = gout;
    }
}

// Round 4
// 1152.836 us; speedup vs baseline: 1.6322x; 1.0582x over previous
//
#include <hip/hip_runtime.h>
#include <hip/hip_fp16.h>
#include <math.h>

// ---------------- init / histogram / norm ----------------

__global__ void zero_i32(int* __restrict__ p, int n) {
    int i = blockIdx.x * blockDim.x + threadIdx.x;
    if (i < n) p[i] = 0;
}

__global__ void hist_k(const int* __restrict__ dst, int E, int* __restrict__ counts) {
    int e = blockIdx.x * blockDim.x + threadIdx.x;
    if (e < E) atomicAdd(&counts[dst[e]], 1);
}

__global__ void dinv_k(const int* __restrict__ counts, float* __restrict__ dinv, int N) {
    int i = blockIdx.x * blockDim.x + threadIdx.x;
    if (i < N) dinv[i] = rsqrtf((float)(counts[i] + 1));  // +1 self-loop
}

// ---------------- 3-pass exclusive scan (1024 elems / block) ----------------

__global__ void scan_pass1(const int* __restrict__ counts, int N, int* __restrict__ bsum) {
    __shared__ int s[256];
    int t = threadIdx.x;
    int base = blockIdx.x * 1024 + t * 4;
    int sum = 0;
    for (int j = 0; j < 4; ++j) { int i = base + j; if (i < N) sum += counts[i]; }
    s[t] = sum; __syncthreads();
    for (int off = 128; off > 0; off >>= 1) {
        if (t < off) s[t] += s[t + off];
        __syncthreads();
    }
    if (t == 0) bsum[blockIdx.x] = s[0];
}

__global__ void scan_pass2(const int* __restrict__ bsum, int nb, int* __restrict__ boff) {
    if (blockIdx.x == 0 && threadIdx.x == 0) {
        int r = 0;
        for (int b = 0; b < nb; ++b) { boff[b] = r; r += bsum[b]; }
    }
}

__global__ void scan_pass3(const int* __restrict__ counts, int N,
                           const int* __restrict__ boff, int* __restrict__ rowptr, int E) {
    __shared__ int s[256];
    int t = threadIdx.x;
    int base = blockIdx.x * 1024 + t * 4;
    int c[4]; int sum = 0;
    for (int j = 0; j < 4; ++j) { int i = base + j; c[j] = (i < N) ? counts[i] : 0; sum += c[j]; }
    s[t] = sum; __syncthreads();
    for (int off = 1; off < 256; off <<= 1) {
        int v = (t >= off) ? s[t - off] : 0;
        __syncthreads();
        s[t] += v;
        __syncthreads();
    }
    int excl = s[t] - sum + boff[blockIdx.x];
    for (int j = 0; j < 4; ++j) {
        int i = base + j;
        if (i < N) { rowptr[i] = excl; excl += c[j]; }
    }
    if (blockIdx.x == 0 && t == 0) rowptr[N] = E;
}

// ---------------- CSR fill: col index only (4B scatter) ----------------
// Edge weights are folded into the prescaled gather buffer (g_hat = dinv*g),
// so no per-edge value is stored at all.

__global__ void fill_k(const int* __restrict__ src, const int* __restrict__ dst, int E,
                       const int* __restrict__ rowptr,
                       int* __restrict__ cursor, int* __restrict__ col) {
    int e = blockIdx.x * blockDim.x + threadIdx.x;
    if (e >= E) return;
    int s = src[e], d = dst[e];
    int pos = rowptr[d] + atomicAdd(&cursor[d], 1);
    col[pos] = s;
}

// ---------------- g0 = x @ W : LDS-tiled, 128 rows x 64 cols per block ----------------
// Emits fp32 g0 (for the 0.1*g0 teleport term) and the PRESCALED fp16 gather
// buffer g0h = dinv[n] * g0[n].

__global__ void __launch_bounds__(256) gemm_k(const float* __restrict__ x,
                                              const float* __restrict__ W,
                                              const float* __restrict__ dinv,
                                              float* __restrict__ g0,
                                              __half* __restrict__ g0h, int N) {
    __shared__ float Ws[128 * 64];    // 32 KB, row-major [k][j]
    __shared__ float xs[128 * 133];   // 68 KB, stride 133 -> conflict-free compute reads
    int t = threadIdx.x;
    for (int i = t; i < 128 * 64; i += 256) Ws[i] = W[i];
    int n0 = blockIdx.x * 128;
    for (int f = t; f < 128 * 32; f += 256) {  // f indexes a float4: r = f>>5, c4 = f&31
        int r = f >> 5, c4 = f & 31;
        int n = n0 + r;
        float4 v = (n < N) ? ((const float4*)x)[(size_t)n * 32 + c4]
                           : make_float4(0.f, 0.f, 0.f, 0.f);
        float* dp = &xs[r * 133 + c4 * 4];
        dp[0] = v.x; dp[1] = v.y; dp[2] = v.z; dp[3] = v.w;
    }
    __syncthreads();
    int tr = t & 15, tc = t >> 4;      // j0 = 4*tr (cols), r0 = 8*tc (rows)
    int j0 = tr * 4, r0 = tc * 8;
    float acc[8][4] = {};
#pragma unroll 4
    for (int k = 0; k < 128; ++k) {
        float4 wv = *(const float4*)&Ws[k * 64 + j0];
#pragma unroll
        for (int i = 0; i < 8; ++i) {
            float xv = xs[(r0 + i) * 133 + k];
            acc[i][0] += xv * wv.x; acc[i][1] += xv * wv.y;
            acc[i][2] += xv * wv.z; acc[i][3] += xv * wv.w;
        }
    }
#pragma unroll
    for (int i = 0; i < 8; ++i) {
        int n = n0 + r0 + i;
        if (n < N) {
            float4 v = make_float4(acc[i][0], acc[i][1], acc[i][2], acc[i][3]);
            *(float4*)&g0[(size_t)n * 64 + j0] = v;
            float dn = dinv[n];
            __half2 h01 = __floats2half2_rn(v.x * dn, v.y * dn);
            __half2 h23 = __floats2half2_rn(v.z * dn, v.w * dn);
            *(__half2*)&g0h[(size_t)n * 64 + j0]     = h01;
            *(__half2*)&g0h[(size_t)n * 64 + j0 + 2] = h23;
        }
    }
}

// ---------------- propagation ----------------
// Buffers hold g_hat = dinv[n]*h[n] (fp16). Row update:
//   S = sum_e g_hat[src_e];  r = 0.9*dinv[d]*(S + g_hat[d]) + 0.1*g0[d]
//   g_hat_out[d] = dinv[d]*r   (or out = r + bias on the final step)
// One wave per row. A row is 64 fp16 = 128 B = 32 lanes of half2, so lanes
// 0-31 gather even edges and lanes 32-63 gather odd edges: one instruction
// covers TWO edges. Cols for 64 edges are fetched with one coalesced load
// and broadcast via v_readlane. 8 edges (4 gathers) in flight per iteration.

__global__ void __launch_bounds__(256) prop_k(const __half* __restrict__ gin,
                                              const float* __restrict__ g0,
                                              __half* __restrict__ gout,
                                              float* __restrict__ outf,
                                              const int* __restrict__ rowptr,
                                              const int* __restrict__ cols,
                                              const float* __restrict__ dinv,
                                              const float* __restrict__ bias,
                                              int N, int final_step) {
    int gw = (blockIdx.x * blockDim.x + threadIdx.x) >> 6;
    int lane = threadIdx.x & 63;
    if (gw >= N) return;
    int beg = rowptr[gw], end = rowptr[gw + 1];
    int deg = end - beg;
    int lh   = lane & 31;   // half2 index within the row (feature pair)
    int pair = lane >> 5;   // 0 = even edge, 1 = odd edge

    const __half2* gin2 = (const __half2*)gin;
    float ax = 0.f, ay = 0.f;

    for (int base = 0; base < deg; base += 64) {
        int m = deg - base; if (m > 64) m = 64;
        int idx = beg + base + (lane < m ? lane : 0);
        int ci = cols[idx];                       // one coalesced 4B/lane load

        int j = 0;
        for (; j + 7 < m; j += 8) {               // 8 edges, 4 paired gathers
            float2 f[4];
#pragma unroll
            for (int u = 0; u < 4; ++u) {
                int ce = __builtin_amdgcn_readlane(ci, j + 2 * u);
                int co = __builtin_amdgcn_readlane(ci, j + 2 * u + 1);
                int c  = pair ? co : ce;
                f[u] = __half22float2(gin2[(size_t)c * 32 + lh]);
            }
#pragma unroll
            for (int u = 0; u < 4; ++u) { ax += f[u].x; ay += f[u].y; }
        }
        for (; j + 1 < m; j += 2) {               // paired tail
            int ce = __builtin_amdgcn_readlane(ci, j);
            int co = __builtin_amdgcn_readlane(ci, j + 1);
            int c  = pair ? co : ce;
            float2 f = __half22float2(gin2[(size_t)c * 32 + lh]);
            ax += f.x; ay += f.y;
        }
        if (j < m) {                              // odd final edge: pair 0 only
            int c = __builtin_amdgcn_readlane(ci, j);
            float2 f = __half22float2(gin2[(size_t)c * 32 + lh]);
            if (!pair) { ax += f.x; ay += f.y; }
        }
    }

    // merge the two edge-parity halves (lane ^ 32 holds the other parity)
    ax += __shfl(ax, lane ^ 32, 64);
    ay += __shfl(ay, lane ^ 32, 64);

    if (pair == 0) {
        float di = dinv[gw];
        float2 gi  = __half22float2(gin2[(size_t)gw * 32 + lh]);  // g_hat[d]
        float2 g0v = ((const float2*)g0)[(size_t)gw * 32 + lh];
        float rx = 0.9f * di * (ax + gi.x) + 0.1f * g0v.x;
        float ry = 0.9f * di * (ay + gi.y) + 0.1f * g0v.y;
        if (final_step) {
            float2 bv = ((const float2*)bias)[lh];
            ((float2*)outf)[(size_t)gw * 32 + lh] = make_float2(rx + bv.x, ry + bv.y);
        } else {
            ((__half2*)gout)[(size_t)gw * 32 + lh] =
                __floats2half2_rn(di * rx, di * ry);
        }
    }
}

// ---------------- launch ----------------

extern "C" void kernel_launch(void* const* d_in, const int* in_sizes, int n_in,
                              void* d_out, int out_size, void* d_ws, size_t ws_size,
                              hipStream_t stream) {
    const float* x  = (const float*)d_in[0];
    const int*   ei = (const int*)d_in[1];
    const float* W  = (const float*)d_in[2];
    const float* b  = (const float*)d_in[3];
    float* out = (float*)d_out;

    const int N = in_sizes[0] / 128;
    const int E = in_sizes[1] / 2;
    const int* src = ei;
    const int* dst = ei + E;

    // workspace carve-up (256 B aligned)
    char* w = (char*)d_ws;
    size_t off = 0;
    auto alloc = [&](size_t bytes) -> void* {
        void* p = w + off;
        off += (bytes + 255) & ~(size_t)255;
        return p;
    };
    float*  g0     = (float*) alloc((size_t)N * 64 * 4);
    __half* g0h    = (__half*)alloc((size_t)N * 64 * 2);
    __half* bufA   = (__half*)alloc((size_t)N * 64 * 2);
    __half* bufB   = (__half*)alloc((size_t)N * 64 * 2);
    int*    cols   = (int*)   alloc((size_t)E * 4);
    int*    rowptr = (int*)   alloc((size_t)(N + 1) * 4);
    int*    counts = (int*)   alloc((size_t)N * 4);
    float*  dinvv  = (float*) alloc((size_t)N * 4);
    const int nb = (N + 1023) / 1024;
    int*    bsum   = (int*)   alloc((size_t)nb * 4);
    int*    boff   = (int*)   alloc((size_t)nb * 4);

    const int nblkN = (N + 255) / 256;
    const int nblkE = (E + 255) / 256;

    // build normalized adjacency (CSR by dst, col-only payload)
    zero_i32<<<nblkN, 256, 0, stream>>>(counts, N);
    hist_k<<<nblkE, 256, 0, stream>>>(dst, E, counts);
    dinv_k<<<nblkN, 256, 0, stream>>>(counts, dinvv, N);
    scan_pass1<<<nb, 256, 0, stream>>>(counts, N, bsum);
    scan_pass2<<<1, 64, 0, stream>>>(bsum, nb, boff);
    scan_pass3<<<nb, 256, 0, stream>>>(counts, N, boff, rowptr, E);
    zero_i32<<<nblkN, 256, 0, stream>>>(counts, N);  // reuse as fill cursor
    fill_k<<<nblkE, 256, 0, stream>>>(src, dst, E, rowptr, counts, cols);

    // g0 = x @ W (propagation commutes with the linear head: (A h) W = A (h W))
    gemm_k<<<(N + 127) / 128, 256, 0, stream>>>(x, W, dinvv, g0, g0h, N);

    // K = 10 APPNP steps, fp16 ping-pong; last step writes fp32 d_out (+bias)
    const int nblkP = (N * 64 + 255) / 256;
    const __half* gin = g0h;
    __half* pp[2] = {bufA, bufB};
    for (int k = 0; k < 10; ++k) {
        const bool fin = (k == 9);
        __half* gout = pp[k & 1];
        prop_k<<<nblkP, 256, 0, stream>>>(gin, g0, gout, out, rowptr, cols,
                                          dinvv, b, N, fin ? 1 : 0);
        gin = gout;
    }
}